// Round 2
// baseline (6922.218 us; speedup 1.0000x reference)
//
#include <hip/hip_runtime.h>
#include <math.h>

#define B_ 64
#define T_ 512
#define H_ 1024
#define V_ 256
#define O_ 1024
#define KFC 2048

typedef short bf16x8 __attribute__((ext_vector_type(8)));
typedef float f32x4 __attribute__((ext_vector_type(4)));
typedef int   i32x4 __attribute__((ext_vector_type(4)));

// ---- workspace layout (bytes) ---- (identical to round 1)
#define OFF_TABLE_F 0                 // [V][H] f32 (W_ih^T + b_ih + b_hh), fwd
#define OFF_TABLE_B 1048576           // same, bwd
#define OFF_XT      2097152           // [T][B] i32 (transposed x)
#define OFF_WHH     2228224           // [d][plane(hi,lo)][cs][kt][nt][lane][8] bf16 (8 MB)
#define OFF_WFC     10616832          // [ob][k32][nt][lane][8] bf16 (4 MB)
#define OFF_HSF     14811136          // [T][B][H] bf16 (64 MB)
#define OFF_HSB     81920000          // [T][B][H] bf16 (64 MB)
#define OFF_XCH     149028864         // [d][pp][plane][cs][bgq][lane][8] bf16 (1 MB)
#define OFF_CNT     150077440         // flags [d][bg][cs] u32 (512 B used; 8 KB reserved)

__device__ __forceinline__ unsigned short f2bf(float f) {
  union { float f; unsigned int u; } un; un.f = f;
  unsigned int u = un.u;
  unsigned int r = u + 0x7FFFu + ((u >> 16) & 1u);
  return (unsigned short)(r >> 16);
}
__device__ __forceinline__ float bf2f(unsigned short h) {
  union { unsigned int u; float f; } un; un.u = ((unsigned int)h) << 16;
  return un.f;
}

// ---------------- prep: tables, transposes, fragment-packed weights ----------------
__global__ void prep_kernel(const int* __restrict__ x,
    const float* __restrict__ WihF, const float* __restrict__ WhhF,
    const float* __restrict__ bihF, const float* __restrict__ bhhF,
    const float* __restrict__ WihB, const float* __restrict__ WhhB,
    const float* __restrict__ bihB, const float* __restrict__ bhhB,
    const float* __restrict__ Wfc,
    float* __restrict__ tableF, float* __restrict__ tableB,
    int* __restrict__ xT, short* __restrict__ whhpack,
    short* __restrict__ wfcpack, unsigned int* __restrict__ cnt)
{
  const long NT1 = 524288, NT2 = 32768, NT3 = 2097152, NT4 = 2097152, NT5 = 2048;
  const long total = NT1 + NT2 + NT3 + NT4 + NT5;
  for (long i = (long)blockIdx.x * blockDim.x + threadIdx.x; i < total;
       i += (long)gridDim.x * blockDim.x) {
    long j = i;
    if (j < NT1) {
      int d = (int)(j >> 18);
      int r = (int)(j & 262143);
      int v = r >> 10, h = r & 1023;
      const float* Wih = d ? WihB : WihF;
      const float* bi  = d ? bihB : bihF;
      const float* bh  = d ? bhhB : bhhF;
      (d ? tableB : tableF)[r] = Wih[h * V_ + v] + bi[h] + bh[h];
      continue;
    }
    j -= NT1;
    if (j < NT2) {
      int t = (int)(j >> 6), bb = (int)(j & 63);
      xT[j] = x[bb * T_ + t];
      continue;
    }
    j -= NT2;
    if (j < NT3) {
      int d = (int)(j >> 20);
      int r = (int)(j & 1048575);
      int jj = r & 7;
      int lanei = (r >> 3) & 63;
      int nti = (r >> 9) & 1;
      int kt = (r >> 10) & 31;
      int csi = r >> 15;
      int c = csi * 32 + nti * 16 + (lanei & 15);
      int k = kt * 32 + (lanei >> 4) * 8 + jj;   // same k-bijection for A and B
      float w = (d ? WhhB : WhhF)[c * H_ + k];
      unsigned short hi = f2bf(w);
      unsigned short lo = f2bf(w - bf2f(hi));
      whhpack[((long)(d * 2 + 0) << 20) + r] = (short)hi;
      whhpack[((long)(d * 2 + 1) << 20) + r] = (short)lo;
      continue;
    }
    j -= NT3;
    if (j < NT4) {
      int jj = (int)(j & 7);
      int lanei = (int)((j >> 3) & 63);
      int nti = (int)((j >> 9) & 3);
      int k32 = (int)((j >> 11) & 63);
      int obi = (int)(j >> 17);
      int o = obi * 64 + nti * 16 + (lanei & 15);
      int k = k32 * 32 + (lanei >> 4) * 8 + jj;
      wfcpack[j] = (short)f2bf(Wfc[(long)o * KFC + k]);
      continue;
    }
    j -= NT4;
    cnt[j] = 0;
  }
}

// ---------------- persistent bidirectional recurrence ----------------
// grid = 128 WGs x 256 thr. WG = (dir, batch-group of 32 rows, 32-col slice).
// LDS: stationary W slice hi/lo fragment-linear, 128 KB. h travels global->VGPR.
// Sync: per-WG monotonic flag words; relaxed poll + one acquire fence per step.
__global__ __launch_bounds__(256, 1)
void rnn_kernel(const int* __restrict__ xT,
                const float* __restrict__ tableF, const float* __restrict__ tableB,
                const short* __restrict__ whhpack,
                short* __restrict__ hsF, short* __restrict__ hsB,
                short* __restrict__ xch, unsigned int* __restrict__ cnt)
{
  extern __shared__ char lds[];
  const int tid = threadIdx.x;
  const int wg = blockIdx.x;
  const int dir = wg >> 6;
  const int bg = (wg >> 5) & 1;
  const int cs = wg & 31;
  const int b0 = bg * 32;
  const int c0 = cs * 32;
  const int lane = tid & 63;
  const int wv = tid >> 6;
  const int mt = wv & 1;       // 16-row tile within 32 rows
  const int nt = wv >> 1;      // 16-col tile within 32 cols
  const float* table = dir ? tableB : tableF;
  short* hs = dir ? hsB : hsF;
  unsigned int* flags = cnt + (dir * 2 + bg) * 32;   // 32 producer flags of my group
  unsigned int* myflag = flags + cs;

  // one-time: W slice (hi+lo) -> LDS, fragment-linear
  {
    const i32x4* wsrc = (const i32x4*)whhpack;
    i32x4* wdst = (i32x4*)lds;
    #pragma unroll
    for (int it = 0; it < 32; ++it) {
      int idx = it * 256 + tid;
      int plane = idx >> 12, rem = idx & 4095;
      wdst[plane * 4096 + rem] =
          wsrc[(size_t)((dir * 2 + plane) * 32 + cs) * 4096 + rem];
    }
  }
  __syncthreads();

  // epilogue addressing (constant per thread)
  const int klocal = nt * 16 + (lane & 15);          // producer's k within its cs-slice
  const int klhi = klocal >> 3, klo3 = klocal & 7;
  const int bgq = bg * 2 + mt;

  for (int s = 0; s < T_; ++s) {
    const int t = dir ? (T_ - 1 - s) : s;
    // gather input contribution early (independent of other WGs; hides under wait)
    float xw[4];
    #pragma unroll
    for (int r = 0; r < 4; ++r) {
      int b = b0 + mt * 16 + (lane >> 4) * 4 + r;
      int vv = xT[t * B_ + b];
      xw[r] = table[vv * H_ + (c0 + nt * 16 + (lane & 15))];
    }
    f32x4 acc = {0.f, 0.f, 0.f, 0.f};

    if (s > 0) {
      // wait for all 32 producers of my group to have published step s-1
      const unsigned int tgt = (unsigned int)s;
      {
        int c = lane & 31;
        while (__hip_atomic_load(&flags[c], __ATOMIC_RELAXED,
                                 __HIP_MEMORY_SCOPE_AGENT) < tgt)
          __builtin_amdgcn_s_sleep(1);
      }
      __builtin_amdgcn_fence(__ATOMIC_ACQUIRE, "agent");  // one inv per step

      // A-fragments straight from global (fragment-linear layout, coalesced dwordx4)
      const short* xsrc = xch + ((size_t)(dir * 2 + ((s - 1) & 1))) * 131072;
      const short* abase = xsrc + bgq * 512 + lane * 8;   // plane0, kt=0
      #pragma unroll 8
      for (int kt = 0; kt < 32; ++kt) {
        bf16x8 ahi = *(const bf16x8*)(abase + kt * 2048);
        bf16x8 alo = *(const bf16x8*)(abase + 65536 + kt * 2048);
        bf16x8 bhi = *(const bf16x8*)(lds + ((0 * 32 + kt) * 2 + nt) * 1024 + lane * 16);
        bf16x8 blo = *(const bf16x8*)(lds + ((1 * 32 + kt) * 2 + nt) * 1024 + lane * 16);
        acc = __builtin_amdgcn_mfma_f32_16x16x32_bf16(ahi, bhi, acc, 0, 0, 0);
        acc = __builtin_amdgcn_mfma_f32_16x16x32_bf16(alo, bhi, acc, 0, 0, 0);
        acc = __builtin_amdgcn_mfma_f32_16x16x32_bf16(ahi, blo, acc, 0, 0, 0);
      }
    }

    // epilogue: tanh, publish h (hi/lo to exchange in fragment order, hi to hs for FC)
    short* xdst = xch + ((size_t)(dir * 2 + (s & 1))) * 131072;
    #pragma unroll
    for (int r = 0; r < 4; ++r) {
      int rowin16 = (lane >> 4) * 4 + r;
      int b = b0 + mt * 16 + rowin16;
      float h = tanhf(acc[r] + xw[r]);
      unsigned short hb = f2bf(h);
      unsigned short lb = f2bf(h - bf2f(hb));
      hs[(size_t)t * (B_ * H_) + b * H_ + (c0 + klocal)] = (short)hb;
      int fidx = cs * 2048 + bgq * 512 + (klhi * 16 + rowin16) * 8 + klo3;
      xdst[fidx] = (short)hb;            // plane 0 (hi)
      xdst[65536 + fidx] = (short)lb;    // plane 1 (lo)
    }
    __syncthreads();  // all waves' stores drained (vmcnt0) before publish
    if (s < T_ - 1 && tid == 0)
      __hip_atomic_store(myflag, (unsigned int)(s + 1), __ATOMIC_RELEASE,
                         __HIP_MEMORY_SCOPE_AGENT);
  }
}

// ---------------- FC: out[B*T,1024] = concat(hf,hb) @ Wfc^T + b ----------------
__global__ __launch_bounds__(256, 4)
void fc_kernel(const short* __restrict__ hsF, const short* __restrict__ hsB,
               const short* __restrict__ wfcpack, const float* __restrict__ bfc,
               float* __restrict__ out)
{
  __shared__ short Alds[64 * 64];          // [row][k] swizzled
  __shared__ short Blds[2 * 4 * 64 * 8];   // fragment-linear
  const int tid = threadIdx.x;
  const int lane = tid & 63;
  const int wv = tid >> 6;
  const int mt2 = wv & 1;
  const int nt2 = wv >> 1;
  const int r0 = blockIdx.x * 64;
  const int ob = blockIdx.y;
  const int bb = r0 >> 9;
  const int t0 = r0 & 511;

  f32x4 z = {0.f, 0.f, 0.f, 0.f};
  f32x4 acc[2][2] = {{z, z}, {z, z}};

  for (int kc = 0; kc < KFC / 64; ++kc) {
    {  // stage A tile (64 rows x 64 k)
      int row = tid >> 2;
      int kq = (tid & 3) * 16;
      int k0 = kc * 64;
      const short* hsrc = (k0 < H_) ? hsF : hsB;
      int kk = (k0 < H_) ? k0 : (k0 - H_);
      const short* src = hsrc + ((size_t)(t0 + row) * B_ + bb) * H_ + kk + kq;
      i32x4 v0 = *(const i32x4*)(src);
      i32x4 v1 = *(const i32x4*)(src + 8);
      int sw = (row & 7) << 4;
      *(i32x4*)((char*)Alds + row * 128 + ((kq * 2) ^ sw)) = v0;
      *(i32x4*)((char*)Alds + row * 128 + ((kq * 2 + 16) ^ sw)) = v1;
    }
    {  // stage B tile (fragment-linear, contiguous copy)
      const i32x4* src = (const i32x4*)(wfcpack + ((size_t)ob * 64 + kc * 2) * 2048);
      i32x4* dst = (i32x4*)Blds;
      dst[tid] = src[tid];
      dst[tid + 256] = src[tid + 256];
    }
    __syncthreads();
    #pragma unroll
    for (int k2 = 0; k2 < 2; ++k2) {
      bf16x8 afr[2];
      #pragma unroll
      for (int mi = 0; mi < 2; ++mi) {
        int row = mt2 * 32 + mi * 16 + (lane & 15);
        int off = (k2 * 64 + (lane >> 4) * 16) ^ ((row & 7) << 4);
        afr[mi] = *(const bf16x8*)((const char*)Alds + row * 128 + off);
      }
      #pragma unroll
      for (int ni = 0; ni < 2; ++ni) {
        int ntg = nt2 * 2 + ni;
        bf16x8 bfr = *(const bf16x8*)((const char*)Blds + ((k2 * 4 + ntg) * 64 + lane) * 16);
        #pragma unroll
        for (int mi = 0; mi < 2; ++mi)
          acc[mi][ni] = __builtin_amdgcn_mfma_f32_16x16x32_bf16(afr[mi], bfr, acc[mi][ni], 0, 0, 0);
      }
    }
    __syncthreads();
  }
  #pragma unroll
  for (int mi = 0; mi < 2; ++mi) {
    int row = r0 + mt2 * 32 + mi * 16 + (lane >> 4) * 4;
    #pragma unroll
    for (int ni = 0; ni < 2; ++ni) {
      int o = ob * 64 + nt2 * 32 + ni * 16 + (lane & 15);
      float bias = bfc[o];
      #pragma unroll
      for (int r = 0; r < 4; ++r)
        out[(size_t)(row + r) * O_ + o] = acc[mi][ni][r] + bias;
    }
  }
}

extern "C" void kernel_launch(void* const* d_in, const int* in_sizes, int n_in,
                              void* d_out, int out_size, void* d_ws, size_t ws_size,
                              hipStream_t stream) {
  const int* x = (const int*)d_in[0];
  const float* WihF = (const float*)d_in[1];
  const float* WhhF = (const float*)d_in[2];
  const float* bihF = (const float*)d_in[3];
  const float* bhhF = (const float*)d_in[4];
  const float* WihB = (const float*)d_in[5];
  const float* WhhB = (const float*)d_in[6];
  const float* bihB = (const float*)d_in[7];
  const float* bhhB = (const float*)d_in[8];
  const float* Wfc  = (const float*)d_in[9];
  const float* bfc  = (const float*)d_in[10];
  float* out = (float*)d_out;
  char* ws = (char*)d_ws;

  float* tableF = (float*)(ws + OFF_TABLE_F);
  float* tableB = (float*)(ws + OFF_TABLE_B);
  int* xT = (int*)(ws + OFF_XT);
  short* whhpack = (short*)(ws + OFF_WHH);
  short* wfcpack = (short*)(ws + OFF_WFC);
  short* hsF = (short*)(ws + OFF_HSF);
  short* hsB = (short*)(ws + OFF_HSB);
  short* xch = (short*)(ws + OFF_XCH);
  unsigned int* cnt = (unsigned int*)(ws + OFF_CNT);

  hipFuncSetAttribute((const void*)rnn_kernel,
                      hipFuncAttributeMaxDynamicSharedMemorySize, 131072);

  prep_kernel<<<dim3(2048), dim3(256), 0, stream>>>(
      x, WihF, WhhF, bihF, bhhF, WihB, WhhB, bihB, bhhB, Wfc,
      tableF, tableB, xT, whhpack, wfcpack, cnt);
  rnn_kernel<<<dim3(128), dim3(256), 131072, stream>>>(
      xT, tableF, tableB, whhpack, hsF, hsB, xch, cnt);
  fc_kernel<<<dim3(512, 16), dim3(256), 0, stream>>>(
      hsF, hsB, wfcpack, bfc, out);
}

// Round 3
// 2402.459 us; speedup vs baseline: 2.8813x; 2.8813x over previous
//
#include <hip/hip_runtime.h>
#include <math.h>

#define B_ 64
#define T_ 512
#define H_ 1024
#define V_ 256
#define O_ 1024
#define KFC 2048

typedef short bf16x8 __attribute__((ext_vector_type(8)));
typedef _Float16 f16x8 __attribute__((ext_vector_type(8)));
typedef float f32x4 __attribute__((ext_vector_type(4)));
typedef int   i32x4 __attribute__((ext_vector_type(4)));
typedef unsigned long long u64x2 __attribute__((ext_vector_type(2)));

// ---- workspace layout (bytes) ----
#define OFF_TABLE_F 0                 // [V][H] f32 (W_ih^T + b_ih + b_hh), fwd
#define OFF_TABLE_B 1048576           // same, bwd
#define OFF_XT      2097152           // [T][B] i32 (transposed x)
#define OFF_WHH     2228224           // fp16 [d][cs][kt][nt][lane][8] (4 MB)
#define OFF_WFC     6422528           // bf16 [ob][k32][nt][lane][8] (4 MB)
#define OFF_HSF     10616832          // [T][B][H] bf16 (64 MB)
#define OFF_HSB     77725696          // [T][B][H] bf16 (64 MB)
#define OFF_XCH     144834560         // fp16 [d][pp][kt][bgq][lane][8] (512 KB)
#define OFF_CNT     145358848         // flags [d][bg][cs] u32 (8 KB reserved)

__device__ __forceinline__ unsigned short f2bf(float f) {
  union { float f; unsigned int u; } un; un.f = f;
  unsigned int u = un.u;
  unsigned int r = u + 0x7FFFu + ((u >> 16) & 1u);
  return (unsigned short)(r >> 16);
}

// ---------------- prep: tables, transposes, fragment-packed weights ----------------
__global__ void prep_kernel(const int* __restrict__ x,
    const float* __restrict__ WihF, const float* __restrict__ WhhF,
    const float* __restrict__ bihF, const float* __restrict__ bhhF,
    const float* __restrict__ WihB, const float* __restrict__ WhhB,
    const float* __restrict__ bihB, const float* __restrict__ bhhB,
    const float* __restrict__ Wfc,
    float* __restrict__ tableF, float* __restrict__ tableB,
    int* __restrict__ xT, short* __restrict__ whhpack,
    short* __restrict__ wfcpack, unsigned int* __restrict__ cnt)
{
  const long NT1 = 524288, NT2 = 32768, NT3 = 2097152, NT4 = 2097152, NT5 = 2048;
  const long total = NT1 + NT2 + NT3 + NT4 + NT5;
  for (long i = (long)blockIdx.x * blockDim.x + threadIdx.x; i < total;
       i += (long)gridDim.x * blockDim.x) {
    long j = i;
    if (j < NT1) {
      int d = (int)(j >> 18);
      int r = (int)(j & 262143);
      int v = r >> 10, h = r & 1023;
      const float* Wih = d ? WihB : WihF;
      const float* bi  = d ? bihB : bihF;
      const float* bh  = d ? bhhB : bhhF;
      (d ? tableB : tableF)[r] = Wih[h * V_ + v] + bi[h] + bh[h];
      continue;
    }
    j -= NT1;
    if (j < NT2) {
      int t = (int)(j >> 6), bb = (int)(j & 63);
      xT[j] = x[bb * T_ + t];
      continue;
    }
    j -= NT2;
    if (j < NT3) {
      int d = (int)(j >> 20);
      int r = (int)(j & 1048575);
      int jj = r & 7;
      int lanei = (r >> 3) & 63;
      int nti = (r >> 9) & 1;
      int kt = (r >> 10) & 31;
      int csi = r >> 15;
      int c = csi * 32 + nti * 16 + (lanei & 15);
      int k = kt * 32 + (lanei >> 4) * 8 + jj;   // same k-bijection for A and B
      float w = (d ? WhhB : WhhF)[c * H_ + k];
      _Float16 wh = (_Float16)w;
      whhpack[((long)d << 20) + r] = __builtin_bit_cast(short, wh);
      continue;
    }
    j -= NT3;
    if (j < NT4) {
      int jj = (int)(j & 7);
      int lanei = (int)((j >> 3) & 63);
      int nti = (int)((j >> 9) & 3);
      int k32 = (int)((j >> 11) & 63);
      int obi = (int)(j >> 17);
      int o = obi * 64 + nti * 16 + (lanei & 15);
      int k = k32 * 32 + (lanei >> 4) * 8 + jj;
      wfcpack[j] = (short)f2bf(Wfc[(long)o * KFC + k]);
      continue;
    }
    j -= NT4;
    cnt[j] = 0;
  }
}

// ---------------- persistent bidirectional recurrence ----------------
// 128 WGs x 256 thr. WG = (dir, bg of 32 rows, cs = 32-col slice).
// LDS: stationary W slice fp16 fragment-linear 64 KB + 2 KB publish bounce.
// Exchange: relaxed agent atomics (sc1, via coherence point) — NO wbl2/inv.
__global__ __launch_bounds__(256, 1)
void rnn_kernel(const int* __restrict__ xT,
                const float* __restrict__ tableF, const float* __restrict__ tableB,
                const short* __restrict__ whhpack,
                short* __restrict__ hsF, short* __restrict__ hsB,
                short* __restrict__ xch, unsigned int* __restrict__ cnt)
{
  extern __shared__ char lds[];   // [0,65536): W frags; [65536,67584): bounce
  const int tid = threadIdx.x;
  const int wg = blockIdx.x;
  const int dir = wg >> 6;
  const int bg = (wg >> 5) & 1;
  const int cs = wg & 31;
  const int b0 = bg * 32;
  const int c0 = cs * 32;
  const int lane = tid & 63;
  const int wv = tid >> 6;
  const int mt = wv & 1;       // 16-row tile within 32 rows
  const int nt = wv >> 1;      // 16-col tile within 32 cols
  const float* table = dir ? tableB : tableF;
  short* hs = dir ? hsB : hsF;
  unsigned int* flags = cnt + (dir * 2 + bg) * 32;   // my group's 32 producer flags
  unsigned int* myflag = flags + cs;
  unsigned long long* xch64 = (unsigned long long*)xch;

  // one-time: W slice -> LDS, fragment-linear (64 KB)
  {
    const i32x4* wsrc = (const i32x4*)whhpack + (size_t)(dir * 32 + cs) * 4096;
    i32x4* wdst = (i32x4*)lds;
    #pragma unroll
    for (int it = 0; it < 16; ++it)
      wdst[it * 256 + tid] = wsrc[it * 256 + tid];
  }
  __syncthreads();

  const int klocal = nt * 16 + (lane & 15);   // producer's k within its slice
  const int bgq = bg * 2 + mt;
  const int rowbase = (lane >> 4) * 4;
  _Float16* bounce = (_Float16*)(lds + 65536);

  for (int s = 0; s < T_; ++s) {
    const int t = dir ? (T_ - 1 - s) : s;
    // gather input contribution early (independent; hides under wait)
    float xw[4];
    #pragma unroll
    for (int r = 0; r < 4; ++r) {
      int b = b0 + mt * 16 + rowbase + r;
      int vv = xT[t * B_ + b];
      xw[r] = table[vv * H_ + c0 + klocal];
    }
    f32x4 z = {0.f, 0.f, 0.f, 0.f};
    f32x4 acc4[4] = {z, z, z, z};

    if (s > 0) {
      // wait: all 32 producers of my group published step s-1 (relaxed poll)
      const unsigned int tgt = (unsigned int)s;
      {
        unsigned int* fp = flags + (lane & 31);
        while (__hip_atomic_load(fp, __ATOMIC_RELAXED,
                                 __HIP_MEMORY_SCOPE_AGENT) < tgt)
          __builtin_amdgcn_s_sleep(1);
      }
      __asm__ __volatile__("" ::: "memory");

      // issue ALL 64 A-fragment loads up front (deep pipeline), then MFMA
      unsigned long long* src = xch64 + (size_t)(dir * 2 + ((s - 1) & 1)) * 16384;
      unsigned long long areg[64];
      #pragma unroll
      for (int q = 0; q < 64; ++q) {
        int kt = q >> 1;
        areg[q] = __hip_atomic_load(
            src + (size_t)(kt * 4 + bgq) * 128 + lane * 2 + (q & 1),
            __ATOMIC_RELAXED, __HIP_MEMORY_SCOPE_AGENT);
      }
      #pragma unroll
      for (int kt = 0; kt < 32; ++kt) {
        u64x2 av = {areg[2 * kt], areg[2 * kt + 1]};
        f16x8 af = __builtin_bit_cast(f16x8, av);
        f16x8 bf = *(const f16x8*)(lds + ((kt * 2 + nt) * 64 + lane) * 16);
        acc4[kt & 3] =
            __builtin_amdgcn_mfma_f32_16x16x32_f16(af, bf, acc4[kt & 3], 0, 0, 0);
      }
    }
    f32x4 accs = (acc4[0] + acc4[1]) + (acc4[2] + acc4[3]);

    // epilogue: tanh; hs (bf16, plain) + bounce (fp16 fragment order, LDS)
    #pragma unroll
    for (int r = 0; r < 4; ++r) {
      int rowin16 = rowbase + r;
      int b = b0 + mt * 16 + rowin16;
      float h = tanhf(accs[r] + xw[r]);
      hs[(size_t)t * (B_ * H_) + b * H_ + c0 + klocal] = (short)f2bf(h);
      bounce[mt * 512 + ((klocal >> 3) * 16 + rowin16) * 8 + (klocal & 7)] =
          (_Float16)h;
    }
    __syncthreads();
    // cooperative publish: 256 x u64 (2 KB slice), relaxed agent (sc1)
    {
      unsigned long long v = *(const unsigned long long*)(lds + 65536 + tid * 8);
      unsigned long long* dst = xch64 + (size_t)(dir * 2 + (s & 1)) * 16384 +
                                (cs * 4 + bg * 2) * 128 + tid;
      __hip_atomic_store(dst, v, __ATOMIC_RELAXED, __HIP_MEMORY_SCOPE_AGENT);
    }
    __syncthreads();  // drains vmcnt(0): data acked at coherence point
    if (s < T_ - 1 && tid == 0)
      __hip_atomic_store(myflag, (unsigned int)(s + 1), __ATOMIC_RELAXED,
                         __HIP_MEMORY_SCOPE_AGENT);
  }
}

// ---------------- FC: out[B*T,1024] = concat(hf,hb) @ Wfc^T + b ----------------
__global__ __launch_bounds__(256, 4)
void fc_kernel(const short* __restrict__ hsF, const short* __restrict__ hsB,
               const short* __restrict__ wfcpack, const float* __restrict__ bfc,
               float* __restrict__ out)
{
  __shared__ short Alds[64 * 64];          // [row][k] swizzled
  __shared__ short Blds[2 * 4 * 64 * 8];   // fragment-linear
  const int tid = threadIdx.x;
  const int lane = tid & 63;
  const int wv = tid >> 6;
  const int mt2 = wv & 1;
  const int nt2 = wv >> 1;
  const int r0 = blockIdx.x * 64;
  const int ob = blockIdx.y;
  const int bb = r0 >> 9;
  const int t0 = r0 & 511;

  f32x4 z = {0.f, 0.f, 0.f, 0.f};
  f32x4 acc[2][2] = {{z, z}, {z, z}};

  for (int kc = 0; kc < KFC / 64; ++kc) {
    {  // stage A tile (64 rows x 64 k)
      int row = tid >> 2;
      int kq = (tid & 3) * 16;
      int k0 = kc * 64;
      const short* hsrc = (k0 < H_) ? hsF : hsB;
      int kk = (k0 < H_) ? k0 : (k0 - H_);
      const short* src = hsrc + ((size_t)(t0 + row) * B_ + bb) * H_ + kk + kq;
      i32x4 v0 = *(const i32x4*)(src);
      i32x4 v1 = *(const i32x4*)(src + 8);
      int sw = (row & 7) << 4;
      *(i32x4*)((char*)Alds + row * 128 + ((kq * 2) ^ sw)) = v0;
      *(i32x4*)((char*)Alds + row * 128 + ((kq * 2 + 16) ^ sw)) = v1;
    }
    {  // stage B tile (fragment-linear, contiguous copy)
      const i32x4* src = (const i32x4*)(wfcpack + ((size_t)ob * 64 + kc * 2) * 2048);
      i32x4* dst = (i32x4*)Blds;
      dst[tid] = src[tid];
      dst[tid + 256] = src[tid + 256];
    }
    __syncthreads();
    #pragma unroll
    for (int k2 = 0; k2 < 2; ++k2) {
      bf16x8 afr[2];
      #pragma unroll
      for (int mi = 0; mi < 2; ++mi) {
        int row = mt2 * 32 + mi * 16 + (lane & 15);
        int off = (k2 * 64 + (lane >> 4) * 16) ^ ((row & 7) << 4);
        afr[mi] = *(const bf16x8*)((const char*)Alds + row * 128 + off);
      }
      #pragma unroll
      for (int ni = 0; ni < 2; ++ni) {
        int ntg = nt2 * 2 + ni;
        bf16x8 bfr = *(const bf16x8*)((const char*)Blds + ((k2 * 4 + ntg) * 64 + lane) * 16);
        #pragma unroll
        for (int mi = 0; mi < 2; ++mi)
          acc[mi][ni] = __builtin_amdgcn_mfma_f32_16x16x32_bf16(afr[mi], bfr, acc[mi][ni], 0, 0, 0);
      }
    }
    __syncthreads();
  }
  #pragma unroll
  for (int mi = 0; mi < 2; ++mi) {
    int row = r0 + mt2 * 32 + mi * 16 + (lane >> 4) * 4;
    #pragma unroll
    for (int ni = 0; ni < 2; ++ni) {
      int o = ob * 64 + nt2 * 32 + ni * 16 + (lane & 15);
      float bias = bfc[o];
      #pragma unroll
      for (int r = 0; r < 4; ++r)
        out[(size_t)(row + r) * O_ + o] = acc[mi][ni][r] + bias;
    }
  }
}

extern "C" void kernel_launch(void* const* d_in, const int* in_sizes, int n_in,
                              void* d_out, int out_size, void* d_ws, size_t ws_size,
                              hipStream_t stream) {
  const int* x = (const int*)d_in[0];
  const float* WihF = (const float*)d_in[1];
  const float* WhhF = (const float*)d_in[2];
  const float* bihF = (const float*)d_in[3];
  const float* bhhF = (const float*)d_in[4];
  const float* WihB = (const float*)d_in[5];
  const float* WhhB = (const float*)d_in[6];
  const float* bihB = (const float*)d_in[7];
  const float* bhhB = (const float*)d_in[8];
  const float* Wfc  = (const float*)d_in[9];
  const float* bfc  = (const float*)d_in[10];
  float* out = (float*)d_out;
  char* ws = (char*)d_ws;

  float* tableF = (float*)(ws + OFF_TABLE_F);
  float* tableB = (float*)(ws + OFF_TABLE_B);
  int* xT = (int*)(ws + OFF_XT);
  short* whhpack = (short*)(ws + OFF_WHH);
  short* wfcpack = (short*)(ws + OFF_WFC);
  short* hsF = (short*)(ws + OFF_HSF);
  short* hsB = (short*)(ws + OFF_HSB);
  short* xch = (short*)(ws + OFF_XCH);
  unsigned int* cnt = (unsigned int*)(ws + OFF_CNT);

  hipFuncSetAttribute((const void*)rnn_kernel,
                      hipFuncAttributeMaxDynamicSharedMemorySize, 67584);

  prep_kernel<<<dim3(2048), dim3(256), 0, stream>>>(
      x, WihF, WhhF, bihF, bhhF, WihB, WhhB, bihB, bhhB, Wfc,
      tableF, tableB, xT, whhpack, wfcpack, cnt);
  rnn_kernel<<<dim3(128), dim3(256), 67584, stream>>>(
      xT, tableF, tableB, whhpack, hsF, hsB, xch, cnt);
  fc_kernel<<<dim3(512, 16), dim3(256), 0, stream>>>(
      hsF, hsB, wfcpack, bfc, out);
}

// Round 4
// 1948.447 us; speedup vs baseline: 3.5527x; 1.2330x over previous
//
#include <hip/hip_runtime.h>
#include <math.h>

#define B_ 64
#define T_ 512
#define H_ 1024
#define V_ 256
#define O_ 1024
#define KFC 2048

typedef short bf16x8 __attribute__((ext_vector_type(8)));
typedef _Float16 f16x8 __attribute__((ext_vector_type(8)));
typedef float f32x4 __attribute__((ext_vector_type(4)));
typedef int   i32x4 __attribute__((ext_vector_type(4)));

// ---- workspace layout (bytes) ----
#define OFF_TABLE_F 0                 // [V][H] f32 (W_ih^T + b_ih + b_hh), fwd
#define OFF_TABLE_B 1048576           // same, bwd
#define OFF_XT      2097152           // [T][B] i32 (transposed x)
#define OFF_WHH     2228224           // fp16 [d][cs][kt][nt][lane][8] (4 MB)
#define OFF_WFC     6422528           // bf16 [ob][k32][nt][lane][8] (4 MB)
#define OFF_HSF     10616832          // [T][B][H] bf16 (64 MB)
#define OFF_HSB     77725696          // [T][B][H] bf16 (64 MB)
#define OFF_XCH     144834560         // fp16 [d][pp][kt][bgq][lane][8] (512 KB)
#define OFF_CNT     145358848         // flags [d][bg][cs] u32 (8 KB reserved)

__device__ __forceinline__ unsigned short f2bf(float f) {
  union { float f; unsigned int u; } un; un.f = f;
  unsigned int u = un.u;
  unsigned int r = u + 0x7FFFu + ((u >> 16) & 1u);
  return (unsigned short)(r >> 16);
}

// ---------------- prep: tables, transposes, fragment-packed weights ----------------
__global__ void prep_kernel(const int* __restrict__ x,
    const float* __restrict__ WihF, const float* __restrict__ WhhF,
    const float* __restrict__ bihF, const float* __restrict__ bhhF,
    const float* __restrict__ WihB, const float* __restrict__ WhhB,
    const float* __restrict__ bihB, const float* __restrict__ bhhB,
    const float* __restrict__ Wfc,
    float* __restrict__ tableF, float* __restrict__ tableB,
    int* __restrict__ xT, short* __restrict__ whhpack,
    short* __restrict__ wfcpack, unsigned int* __restrict__ cnt)
{
  const long NT1 = 524288, NT2 = 32768, NT3 = 2097152, NT4 = 2097152, NT5 = 2048;
  const long total = NT1 + NT2 + NT3 + NT4 + NT5;
  for (long i = (long)blockIdx.x * blockDim.x + threadIdx.x; i < total;
       i += (long)gridDim.x * blockDim.x) {
    long j = i;
    if (j < NT1) {
      int d = (int)(j >> 18);
      int r = (int)(j & 262143);
      int v = r >> 10, h = r & 1023;
      const float* Wih = d ? WihB : WihF;
      const float* bi  = d ? bihB : bihF;
      const float* bh  = d ? bhhB : bhhF;
      (d ? tableB : tableF)[r] = Wih[h * V_ + v] + bi[h] + bh[h];
      continue;
    }
    j -= NT1;
    if (j < NT2) {
      int t = (int)(j >> 6), bb = (int)(j & 63);
      xT[j] = x[bb * T_ + t];
      continue;
    }
    j -= NT2;
    if (j < NT3) {
      int d = (int)(j >> 20);
      int r = (int)(j & 1048575);
      int jj = r & 7;
      int lanei = (r >> 3) & 63;
      int nti = (r >> 9) & 1;
      int kt = (r >> 10) & 31;
      int csi = r >> 15;
      int c = csi * 32 + nti * 16 + (lanei & 15);
      int k = kt * 32 + (lanei >> 4) * 8 + jj;   // same k-bijection for A and B
      float w = (d ? WhhB : WhhF)[c * H_ + k];
      _Float16 wh = (_Float16)w;
      whhpack[((long)d << 20) + r] = __builtin_bit_cast(short, wh);
      continue;
    }
    j -= NT3;
    if (j < NT4) {
      int jj = (int)(j & 7);
      int lanei = (int)((j >> 3) & 63);
      int nti = (int)((j >> 9) & 3);
      int k32 = (int)((j >> 11) & 63);
      int obi = (int)(j >> 17);
      int o = obi * 64 + nti * 16 + (lanei & 15);
      int k = k32 * 32 + (lanei >> 4) * 8 + jj;
      wfcpack[j] = (short)f2bf(Wfc[(long)o * KFC + k]);
      continue;
    }
    j -= NT4;
    cnt[j] = 0;
  }
}

// ---------------- persistent bidirectional recurrence ----------------
// 128 WGs x 256 thr. WG = (dir, bg of 32 rows, cs = 32-col slice).
// LDS: [0,64K) W frags; [64K,128K) A staging; [128K,+2K) publish bounce.
// Exchange via relaxed agent atomics (sc1): thread-disjoint u64 loads ->
// ds_write (deep vmcnt pipeline, no dup), frags re-read from LDS.
__global__ __launch_bounds__(256, 1)
void rnn_kernel(const int* __restrict__ xT,
                const float* __restrict__ tableF, const float* __restrict__ tableB,
                const short* __restrict__ whhpack,
                short* __restrict__ hsF, short* __restrict__ hsB,
                short* __restrict__ xch, unsigned int* __restrict__ cnt)
{
  extern __shared__ char lds[];
  const int tid = threadIdx.x;
  const int wg = blockIdx.x;
  const int dir = wg >> 6;
  const int bg = (wg >> 5) & 1;
  const int cs = wg & 31;
  const int b0 = bg * 32;
  const int c0 = cs * 32;
  const int lane = tid & 63;
  const int wv = tid >> 6;
  const int mt = wv & 1;       // 16-row tile within 32 rows
  const int nt = wv >> 1;      // 16-col tile within 32 cols
  const float* table = dir ? tableB : tableF;
  short* hs = dir ? hsB : hsF;
  unsigned int* flags = cnt + (dir * 2 + bg) * 32;   // my group's 32 producer flags
  unsigned int* myflag = flags + cs;
  unsigned long long* xch64 = (unsigned long long*)xch;

  // one-time: W slice -> LDS, fragment-linear (64 KB)
  {
    const i32x4* wsrc = (const i32x4*)whhpack + (size_t)(dir * 32 + cs) * 4096;
    i32x4* wdst = (i32x4*)lds;
    #pragma unroll
    for (int it = 0; it < 16; ++it)
      wdst[it * 256 + tid] = wsrc[it * 256 + tid];
  }
  __syncthreads();

  const int klocal = nt * 16 + (lane & 15);   // producer's k within its slice
  const int rowbase = (lane >> 4) * 4;
  _Float16* bounce = (_Float16*)(lds + 131072);

  for (int s = 0; s < T_; ++s) {
    const int t = dir ? (T_ - 1 - s) : s;
    // gather input contribution early (issues before poll; hides under wait)
    float xw[4];
    #pragma unroll
    for (int r = 0; r < 4; ++r) {
      int b = b0 + mt * 16 + rowbase + r;
      int vv = xT[t * B_ + b];
      xw[r] = table[vv * H_ + c0 + klocal];
    }
    f32x4 z = {0.f, 0.f, 0.f, 0.f};
    f32x4 acc4[4] = {z, z, z, z};

    if (s > 0) {
      // wave 0 polls the 32 producer flags; others wait at the barrier
      const unsigned int tgt = (unsigned int)s;
      if (wv == 0) {
        unsigned int* fp = flags + (lane & 31);
        while (__hip_atomic_load(fp, __ATOMIC_RELAXED,
                                 __HIP_MEMORY_SCOPE_AGENT) < tgt)
          __builtin_amdgcn_s_sleep(1);
      }
      __syncthreads();
      __asm__ __volatile__("" ::: "memory");

      // stage A (64 KB, thread-disjoint): 32 u64 loads -> ds_write pipeline
      unsigned long long* src = xch64 + (size_t)(dir * 2 + ((s - 1) & 1)) * 16384;
      unsigned long long* adst = (unsigned long long*)(lds + 65536);
      unsigned long long areg[32];
      #pragma unroll
      for (int i = 0; i < 32; ++i) {
        int w = i * 256 + tid;
        int inner = w & 127, mtt = (w >> 7) & 1, kt = w >> 8;
        areg[i] = __hip_atomic_load(
            src + (size_t)(kt * 4 + bg * 2 + mtt) * 128 + inner,
            __ATOMIC_RELAXED, __HIP_MEMORY_SCOPE_AGENT);
      }
      #pragma unroll
      for (int i = 0; i < 32; ++i)
        adst[i * 256 + tid] = areg[i];
      __syncthreads();

      #pragma unroll
      for (int kt = 0; kt < 32; ++kt) {
        f16x8 af = *(const f16x8*)(lds + 65536 + (kt * 2 + mt) * 1024 + lane * 16);
        f16x8 bf = *(const f16x8*)(lds + (kt * 2 + nt) * 1024 + lane * 16);
        acc4[kt & 3] =
            __builtin_amdgcn_mfma_f32_16x16x32_f16(af, bf, acc4[kt & 3], 0, 0, 0);
      }
    }
    f32x4 accs = (acc4[0] + acc4[1]) + (acc4[2] + acc4[3]);

    // epilogue: fast tanh; hs (bf16 planar) + bounce (fp16 fragment order)
    #pragma unroll
    for (int r = 0; r < 4; ++r) {
      int rowin16 = rowbase + r;
      int b = b0 + mt * 16 + rowin16;
      float zz = accs[r] + xw[r];
      float e = __expf(2.0f * zz);
      float h = (e - 1.0f) / (e + 1.0f);
      hs[(size_t)t * (B_ * H_) + b * H_ + c0 + klocal] = (short)f2bf(h);
      bounce[mt * 512 + ((klocal >> 3) * 16 + rowin16) * 8 + (klocal & 7)] =
          (_Float16)h;
    }
    __syncthreads();
    // cooperative publish: 256 x u64 (2 KB slice), relaxed agent (sc1)
    {
      unsigned long long v = *(const unsigned long long*)(lds + 131072 + tid * 8);
      unsigned long long* dst = xch64 + (size_t)(dir * 2 + (s & 1)) * 16384 +
                                (cs * 4 + bg * 2) * 128 + tid;
      __hip_atomic_store(dst, v, __ATOMIC_RELAXED, __HIP_MEMORY_SCOPE_AGENT);
    }
    __syncthreads();  // drains vmcnt(0): data acked at coherence point
    if (s < T_ - 1 && tid == 0)
      __hip_atomic_store(myflag, (unsigned int)(s + 1), __ATOMIC_RELAXED,
                         __HIP_MEMORY_SCOPE_AGENT);
  }
}

// ---------------- FC: out[B*T,1024] = concat(hf,hb) @ Wfc^T + b ----------------
__global__ __launch_bounds__(256, 4)
void fc_kernel(const short* __restrict__ hsF, const short* __restrict__ hsB,
               const short* __restrict__ wfcpack, const float* __restrict__ bfc,
               float* __restrict__ out)
{
  __shared__ short Alds[64 * 64];          // [row][k] swizzled
  __shared__ short Blds[2 * 4 * 64 * 8];   // fragment-linear
  const int tid = threadIdx.x;
  const int lane = tid & 63;
  const int wv = tid >> 6;
  const int mt2 = wv & 1;
  const int nt2 = wv >> 1;
  const int r0 = blockIdx.x * 64;
  const int ob = blockIdx.y;
  const int bb = r0 >> 9;
  const int t0 = r0 & 511;

  f32x4 z = {0.f, 0.f, 0.f, 0.f};
  f32x4 acc[2][2] = {{z, z}, {z, z}};

  for (int kc = 0; kc < KFC / 64; ++kc) {
    {  // stage A tile (64 rows x 64 k)
      int row = tid >> 2;
      int kq = (tid & 3) * 16;
      int k0 = kc * 64;
      const short* hsrc = (k0 < H_) ? hsF : hsB;
      int kk = (k0 < H_) ? k0 : (k0 - H_);
      const short* src = hsrc + ((size_t)(t0 + row) * B_ + bb) * H_ + kk + kq;
      i32x4 v0 = *(const i32x4*)(src);
      i32x4 v1 = *(const i32x4*)(src + 8);
      int sw = (row & 7) << 4;
      *(i32x4*)((char*)Alds + row * 128 + ((kq * 2) ^ sw)) = v0;
      *(i32x4*)((char*)Alds + row * 128 + ((kq * 2 + 16) ^ sw)) = v1;
    }
    {  // stage B tile (fragment-linear, contiguous copy)
      const i32x4* src = (const i32x4*)(wfcpack + ((size_t)ob * 64 + kc * 2) * 2048);
      i32x4* dst = (i32x4*)Blds;
      dst[tid] = src[tid];
      dst[tid + 256] = src[tid + 256];
    }
    __syncthreads();
    #pragma unroll
    for (int k2 = 0; k2 < 2; ++k2) {
      bf16x8 afr[2];
      #pragma unroll
      for (int mi = 0; mi < 2; ++mi) {
        int row = mt2 * 32 + mi * 16 + (lane & 15);
        int off = (k2 * 64 + (lane >> 4) * 16) ^ ((row & 7) << 4);
        afr[mi] = *(const bf16x8*)((const char*)Alds + row * 128 + off);
      }
      #pragma unroll
      for (int ni = 0; ni < 2; ++ni) {
        int ntg = nt2 * 2 + ni;
        bf16x8 bfr = *(const bf16x8*)((const char*)Blds + ((k2 * 4 + ntg) * 64 + lane) * 16);
        #pragma unroll
        for (int mi = 0; mi < 2; ++mi)
          acc[mi][ni] = __builtin_amdgcn_mfma_f32_16x16x32_bf16(afr[mi], bfr, acc[mi][ni], 0, 0, 0);
      }
    }
    __syncthreads();
  }
  #pragma unroll
  for (int mi = 0; mi < 2; ++mi) {
    int row = r0 + mt2 * 32 + mi * 16 + (lane >> 4) * 4;
    #pragma unroll
    for (int ni = 0; ni < 2; ++ni) {
      int o = ob * 64 + nt2 * 32 + ni * 16 + (lane & 15);
      float bias = bfc[o];
      #pragma unroll
      for (int r = 0; r < 4; ++r)
        out[(size_t)(row + r) * O_ + o] = acc[mi][ni][r] + bias;
    }
  }
}

extern "C" void kernel_launch(void* const* d_in, const int* in_sizes, int n_in,
                              void* d_out, int out_size, void* d_ws, size_t ws_size,
                              hipStream_t stream) {
  const int* x = (const int*)d_in[0];
  const float* WihF = (const float*)d_in[1];
  const float* WhhF = (const float*)d_in[2];
  const float* bihF = (const float*)d_in[3];
  const float* bhhF = (const float*)d_in[4];
  const float* WihB = (const float*)d_in[5];
  const float* WhhB = (const float*)d_in[6];
  const float* bihB = (const float*)d_in[7];
  const float* bhhB = (const float*)d_in[8];
  const float* Wfc  = (const float*)d_in[9];
  const float* bfc  = (const float*)d_in[10];
  float* out = (float*)d_out;
  char* ws = (char*)d_ws;

  float* tableF = (float*)(ws + OFF_TABLE_F);
  float* tableB = (float*)(ws + OFF_TABLE_B);
  int* xT = (int*)(ws + OFF_XT);
  short* whhpack = (short*)(ws + OFF_WHH);
  short* wfcpack = (short*)(ws + OFF_WFC);
  short* hsF = (short*)(ws + OFF_HSF);
  short* hsB = (short*)(ws + OFF_HSB);
  short* xch = (short*)(ws + OFF_XCH);
  unsigned int* cnt = (unsigned int*)(ws + OFF_CNT);

  hipFuncSetAttribute((const void*)rnn_kernel,
                      hipFuncAttributeMaxDynamicSharedMemorySize, 133120);

  prep_kernel<<<dim3(2048), dim3(256), 0, stream>>>(
      x, WihF, WhhF, bihF, bhhF, WihB, WhhB, bihB, bhhB, Wfc,
      tableF, tableB, xT, whhpack, wfcpack, cnt);
  rnn_kernel<<<dim3(128), dim3(256), 133120, stream>>>(
      xT, tableF, tableB, whhpack, hsF, hsB, xch, cnt);
  fc_kernel<<<dim3(512, 16), dim3(256), 0, stream>>>(
      hsF, hsB, wfcpack, bfc, out);
}